// Round 9
// baseline (444.014 us; speedup 1.0000x reference)
//
#include <hip/hip_runtime.h>
#include <math.h>

#define NIMG 116          // 4*29 images
#define TW 118            // output tile width  (phase-1 columns = TW+10 = 128)
#define TH 16             // output tile height (strips of 8 rows, 2 strips)

// 11-tap Gaussian (size=11, sigma=1.5), fp32 values matching the reference.
static constexpr float W[11] = {
    0.00102838f, 0.00759876f, 0.03600078f, 0.10936075f, 0.21300554f,
    0.26601172f, 0.21300554f, 0.10936075f, 0.03600078f, 0.00759876f,
    0.00102838f};

typedef float f2 __attribute__((ext_vector_type(2)));

__device__ __forceinline__ f2 pkfma(f2 a, f2 b, f2 c) {
#if __has_builtin(__builtin_elementwise_fma)
    return __builtin_elementwise_fma(a, b, c);
#else
    f2 r; r.x = fmaf(a.x, b.x, c.x); r.y = fmaf(a.y, b.y, c.y); return r;
#endif
}

__device__ __forceinline__ float frcp(float x) {
    return __builtin_amdgcn_rcpf(x);
}

__device__ __forceinline__ float fsig(float x) {
    float e = __builtin_amdgcn_exp2f(x * -1.4426950408889634f);
    return frcp(1.0f + e);
}

// ---------------------------------------------------------------------------
// Packed-FP32 + bank-swizzled LDS (R6 math, bit-identical) + R9 two-tile
// software pipeline.
// R5: pkfma halved VALU issue but f2 LDS layout -> 20M conflicts, net 0.
// R6: float4-column {mu1,mu2,xx,xy} + XOR swizzle -> conflicts 0, L0 181 µs,
//     total 414.5 (best).
// R7: LDS-staged loads REGRESSED (+10 µs): strided loads are L2-absorbed;
//     load restructuring exonerated.
// R8: pinned weight-pair VGPRs: no codegen change (VGPR 52 both) — weight
//     remat theory falsified. L0 idle (35%) is latency/barrier structure.
// R9: PIPE2 — each block runs 2 vertically-adjacent tiles. Tile B's 36
//     loads issue right after the A-phase barrier and fly during A's
//     phase-2 FMAs (~2500 cyc) -> B's vertical phase starts with data
//     resident. Halves block count, one reduction/atomic per 2 tiles.
//     LDS shared (B writes after barrier ending A's reads). Peak VGPR
//     ~100-116 < 128 cap.
// LDS: planes 8192 f + yy 2048 f = 40960 B -> exactly 4 blocks/CU
// (prior session: 32 KB/5 blocks raised HBM traffic 12%; keep locality).
// History: R1 keep-alive-on-loads -5 µs; R2 grid.sync raced; R4 tail
// serialization +35 µs. Structure = proven 5 launches + finalize.
// ---------------------------------------------------------------------------
template <int N, int M, bool SIG, bool POOL, bool SKIPYY, bool NARROW, bool PIPE2>
__global__ __launch_bounds__(256, 4)
void ssim_kernel(const float* __restrict__ X, const float* __restrict__ Y,
                 float* __restrict__ accSsim, float* __restrict__ accCs,
                 float* __restrict__ poolX, float* __restrict__ poolY) {
    __shared__ float smem[10240];              // 40960 B -> 4 blocks/CU
    const int tid = threadIdx.x;
    const int img = blockIdx.z;
    const int ox0 = NARROW ? 0 : blockIdx.x * TW;
    const int c  = tid & 127;      // tile-local column 0..127
    const int s  = tid >> 7;       // strip 0/1 (rows 8s .. 8s+7)
    const int ci = ox0 + c;        // global column
    constexpr int half = N >> 1;
    const int powned = NARROW ? N : min(TW, N - ox0);  // pool column ownership
    const long base = (long)img * N * N;
    const float* __restrict__ Xb = X + base;
    const float* __restrict__ Yb = Y + base;

    f2 WP[11];
#pragma unroll
    for (int t = 0; t < 11; t++) WP[t] = (f2){W[t], W[t]};

    // ---- phase 1 load: 18 rows/thread into registers -----------------------
    auto load_tile = [&](int oy0, f2* xy) {
        const bool interior = (oy0 + 25 < N) && (ox0 + 127 < N);
        if (interior) {
            const float* __restrict__ xp = Xb + (long)(oy0 + 8 * s) * N + ci;
            const float* __restrict__ yp = Yb + (long)(oy0 + 8 * s) * N + ci;
#pragma unroll
            for (int i = 0; i < 18; i++) {
                xy[i].x = xp[(long)i * N];
                xy[i].y = yp[(long)i * N];
            }
        } else {
            const int cic = min(ci, N - 1);
#pragma unroll
            for (int i = 0; i < 18; i++) {
                int rc = min(oy0 + 8 * s + i, N - 1);
                xy[i].x = Xb[(long)rc * N + cic];
                xy[i].y = Yb[(long)rc * N + cic];
            }
        }
        __builtin_amdgcn_sched_barrier(0);   // pin issue point (pipeline fence)
    };

    // ---- phase 1b/1c: sigmoid, vertical filter, pool, LDS store ------------
    auto vert_store = [&](int oy0, f2* xy) {
        if constexpr (SIG) {
#pragma unroll
            for (int i = 0; i < 18; i++) xy[i].x = fsig(xy[i].x);
        }
        f2 a01[8], a23[8];
        float ayy[SKIPYY ? 1 : 8];
#pragma unroll
        for (int o = 0; o < 8; o++) {
            a01[o] = (f2){0.f, 0.f};
            a23[o] = (f2){0.f, 0.f};
            if constexpr (!SKIPYY) ayy[o] = 0.f;
        }
#pragma unroll
        for (int i = 0; i < 18; i++) {
            f2 v01 = xy[i];
            f2 xb = (f2){v01.x, v01.x};
            f2 v23 = xb * v01;                       // {x*x, x*y} packed mul
            float yy;
            if constexpr (!SKIPYY) yy = v01.y * v01.y;
#pragma unroll
            for (int o = 0; o < 8; o++) {
                int t = i - o;
                if (t >= 0 && t < 11) {              // folds statically
                    a01[o] = pkfma(WP[t], v01, a01[o]);
                    a23[o] = pkfma(WP[t], v23, a23[o]);
                    if constexpr (!SKIPYY) ayy[o] = fmaf(W[t], yy, ayy[o]);
                }
            }
        }
        if constexpr (POOL) {
            float cx[4], cy[4];
#pragma unroll
            for (int p = 0; p < 4; p++) {
                cx[p] = xy[2 * p].x + xy[2 * p + 1].x;
                cy[p] = xy[2 * p].y + xy[2 * p + 1].y;
            }
#pragma unroll
            for (int p = 0; p < 4; p++) {
                float rx = __shfl_down(cx[p], 1, 64);   // column c+1 (same wave)
                float ry = __shfl_down(cy[p], 1, 64);
                if (!(c & 1) && c < powned) {
                    int orow = (oy0 + 8 * s + 2 * p) >> 1;
                    int ocol = ci >> 1;
                    long pb = (long)img * half * half + (long)orow * half + ocol;
                    poolX[pb] = 0.25f * (cx[p] + rx);
                    poolY[pb] = 0.25f * (cy[p] + ry);
                }
            }
        }
        // LDS write: float4 column {mu1,mu2,xx,xy} at XOR-swizzled position
        // main plane floats [0,8192); yy scalar plane [8192,10240)
#pragma unroll
        for (int o = 0; o < 8; o++) {
            int rr = 8 * s + o;
            int phys = c ^ (((c >> 3) + rr) & 7);       // bijective per row
            float4 v;
            v.x = a01[o].x; v.y = a01[o].y; v.z = a23[o].x; v.w = a23[o].y;
            *(float4*)&smem[rr * 512 + phys * 4] = v;
            if constexpr (!SKIPYY) {
                int ch = c >> 2;
                int pc = ch ^ (((ch >> 3) + rr) & 7);   // f4-chunk swizzle
                smem[8192 + rr * 128 + pc * 4 + (c & 3)] = ayy[o];
            }
        }
    };

    // ---- phase 2: horizontal filter + SSIM map -----------------------------
    const float C1 = 1e-4f, C2 = 9e-4f;
    auto phase2 = [&](int oy0, float& scs, float& sss) {
        const int r = tid >> 4;    // output row within tile
        const int k = tid & 15;    // 8-px column segment
        if (k < 15) {              // segment base 8k must be < 118
            f2 a01h[8], a23h[8];
#pragma unroll
            for (int j = 0; j < 8; j++) {
                a01h[j] = (f2){0.f, 0.f};
                a23h[j] = (f2){0.f, 0.f};
            }
#pragma unroll
            for (int m = 0; m < 18; m++) {
                int col = 8 * k + m;                    // may be 128/129 @k=14
                int g = (k + (m >> 3) + r) & 7;         // == ((col>>3)+r)&7
                int phys = (col ^ g) & 127;             // wrap: garbage masked
                const float4 v4 = *(const float4*)&smem[r * 512 + phys * 4];
                f2 v01 = (f2){v4.x, v4.y};
                f2 v23 = (f2){v4.z, v4.w};
#pragma unroll
                for (int j = 0; j < 8; j++) {
                    int t = m - j;
                    if (t >= 0 && t < 11) {             // folds statically
                        a01h[j] = pkfma(WP[t], v01, a01h[j]);
                        a23h[j] = pkfma(WP[t], v23, a23h[j]);
                    }
                }
            }
            float oyy[8];
            if constexpr (!SKIPYY) {
                float rgs[20];
#pragma unroll
                for (int j5 = 0; j5 < 5; j5++) {
                    int ch = 2 * k + j5;                // may be 32 @k=14
                    int pc = (ch ^ (((ch >> 3) + r) & 7)) & 31;
                    const float4 v4 = *(const float4*)&smem[8192 + r * 128 + pc * 4];
                    rgs[4 * j5 + 0] = v4.x; rgs[4 * j5 + 1] = v4.y;
                    rgs[4 * j5 + 2] = v4.z; rgs[4 * j5 + 3] = v4.w;
                }
#pragma unroll
                for (int j = 0; j < 8; j++) {
                    float a = 0.f;
#pragma unroll
                    for (int t = 0; t < 11; t++) a = fmaf(W[t], rgs[j + t], a);
                    oyy[j] = a;
                }
            }
            const int gy = oy0 + r;
            const bool rowok = gy < M;          // uniform per thread, hoisted
#pragma unroll
            for (int j = 0; j < 8; j++) {
                int lc = 8 * k + j;
                int gx = ox0 + lc;
                if (lc < TW && gx < M && rowok) {
                    float mu1 = a01h[j].x, mu2 = a01h[j].y;
                    float exx = a23h[j].x, exy = a23h[j].y;
                    float m11 = mu1 * mu1, m22 = mu2 * mu2, m12 = mu1 * mu2;
                    float s1 = exx - m11;
                    float s2 = SKIPYY ? (mu2 - m22) : (oyy[j] - m22);
                    float s12 = exy - m12;
                    float cs = (2.f * s12 + C2) * frcp(s1 + s2 + C2);
                    float ssim = (2.f * m12 + C1) * frcp(m11 + m22 + C1) * cs;
                    scs += cs; sss += ssim;
                }
            }
        }
    };

    float scs = 0.f, sss = 0.f;
    if constexpr (PIPE2) {
        const int oyA = (int)(blockIdx.y * 2) * TH;
        const int oyB = oyA + TH;
        f2 xyA[18], xyB[18];
        load_tile(oyA, xyA);
        vert_store(oyA, xyA);
        __syncthreads();
        load_tile(oyB, xyB);       // B loads fly during phase2(A)
        phase2(oyA, scs, sss);
        __syncthreads();           // A's LDS reads done -> B may overwrite
        vert_store(oyB, xyB);      // vmcnt wait lands here (latency hidden)
        __syncthreads();
        phase2(oyB, scs, sss);
    } else {
        const int oy0 = blockIdx.y * TH;
        f2 xy[18];
        load_tile(oy0, xy);
        vert_store(oy0, xy);
        __syncthreads();
        phase2(oy0, scs, sss);
    }

    // block reduction (reuse smem after barrier); one atomic per block
    for (int off = 32; off > 0; off >>= 1) {
        scs += __shfl_down(scs, off, 64);
        sss += __shfl_down(sss, off, 64);
    }
    __syncthreads();
    int lane = tid & 63, wv = tid >> 6;
    if (lane == 0) { smem[wv] = scs; smem[4 + wv] = sss; }
    __syncthreads();
    if (tid == 0) {
        atomicAdd(&accCs[img],   smem[0] + smem[1] + smem[2] + smem[3]);
        atomicAdd(&accSsim[img], smem[4] + smem[5] + smem[6] + smem[7]);
    }
}

// acc layout: level l -> [l*2*NIMG .. +NIMG) ssim sums, [+NIMG .. +2*NIMG) cs sums
__global__ __launch_bounds__(128)
void finalize_kernel(const float* __restrict__ acc, float* __restrict__ out) {
    const float wts[5] = {0.0448f, 0.2856f, 0.3001f, 0.2363f, 0.1333f};
    const int Ms[5] = {502, 246, 118, 54, 22};
    int t = threadIdx.x;
    float v = 0.f;
    if (t < NIMG) {
        float prod = 1.f;
#pragma unroll
        for (int l = 0; l < 5; l++) {
            float inv = 1.0f / ((float)Ms[l] * (float)Ms[l]);
            float m = (l < 4) ? acc[l * 2 * NIMG + NIMG + t] * inv   // cs mean
                              : acc[l * 2 * NIMG + t] * inv;          // ssim mean
            m = fmaxf(m, 0.f);                                        // relu
            prod *= powf(m, wts[l]);
        }
        v = prod;
    }
    for (int off = 32; off > 0; off >>= 1) v += __shfl_down(v, off, 64);
    __shared__ float red[2];
    if ((t & 63) == 0) red[t >> 6] = v;
    __syncthreads();
    if (t == 0) out[0] = 1.0f - (red[0] + red[1]) / (float)NIMG;
}

extern "C" void kernel_launch(void* const* d_in, const int* in_sizes, int n_in,
                              void* d_out, int out_size, void* d_ws, size_t ws_size,
                              hipStream_t stream) {
    const float* logits = (const float*)d_in[0];
    const float* targets = (const float*)d_in[1];
    float* out = (float*)d_out;
    float* ws = (float*)d_ws;

    // workspace layout (floats)
    float* acc = ws;                               // 5*2*116 = 1160 floats
    size_t off = 1280;
    float* X1 = ws + off; off += (size_t)NIMG * 256 * 256;
    float* Y1 = ws + off; off += (size_t)NIMG * 256 * 256;
    float* X2 = ws + off; off += (size_t)NIMG * 128 * 128;
    float* Y2 = ws + off; off += (size_t)NIMG * 128 * 128;
    float* X3 = ws + off; off += (size_t)NIMG * 64 * 64;
    float* Y3 = ws + off; off += (size_t)NIMG * 64 * 64;
    float* X4 = ws + off; off += (size_t)NIMG * 32 * 32;
    float* Y4 = ws + off; off += (size_t)NIMG * 32 * 32;

    hipMemsetAsync(acc, 0, 1160 * sizeof(float), stream);

    // level 0: sigmoid + pool fused, binary targets -> SKIPYY, PIPE2 (16 pairs)
    {
        dim3 grid((512 + TW - 1) / TW, 512 / TH / 2, NIMG);
        ssim_kernel<512, 502, true, true, true, false, true><<<grid, 256, 0, stream>>>(
            logits, targets, acc, acc + NIMG, X1, Y1);
    }
    // level 1: N=256, wide tiles, PIPE2 (8 pairs)
    {
        dim3 grid((256 + TW - 1) / TW, 256 / TH / 2, NIMG);
        ssim_kernel<256, 246, false, true, false, false, true><<<grid, 256, 0, stream>>>(
            X1, Y1, acc + 2 * NIMG, acc + 3 * NIMG, X2, Y2);
    }
    // level 2: N=128, single x-tile
    {
        dim3 grid(1, 128 / TH, NIMG);
        ssim_kernel<128, 118, false, true, false, true, false><<<grid, 256, 0, stream>>>(
            X2, Y2, acc + 4 * NIMG, acc + 5 * NIMG, X3, Y3);
    }
    // level 3: N=64, single x-tile
    {
        dim3 grid(1, 64 / TH, NIMG);
        ssim_kernel<64, 54, false, true, false, true, false><<<grid, 256, 0, stream>>>(
            X3, Y3, acc + 6 * NIMG, acc + 7 * NIMG, X4, Y4);
    }
    // level 4: N=32, single x-tile, no pool
    {
        dim3 grid(1, 32 / TH, NIMG);
        ssim_kernel<32, 22, false, false, false, true, false><<<grid, 256, 0, stream>>>(
            X4, Y4, acc + 8 * NIMG, acc + 9 * NIMG, nullptr, nullptr);
    }

    finalize_kernel<<<1, 128, 0, stream>>>(acc, out);
}

// Round 10
// 409.804 us; speedup vs baseline: 1.0835x; 1.0835x over previous
//
#include <hip/hip_runtime.h>
#include <math.h>

#define NIMG 116          // 4*29 images
#define TW 118            // output tile width  (phase-1 columns = TW+10 = 128)
#define TH 16             // output tile height (strips of 8 rows, 2 strips)

// 11-tap Gaussian (size=11, sigma=1.5), fp32 values matching the reference.
static constexpr float W[11] = {
    0.00102838f, 0.00759876f, 0.03600078f, 0.10936075f, 0.21300554f,
    0.26601172f, 0.21300554f, 0.10936075f, 0.03600078f, 0.00759876f,
    0.00102838f};

typedef float f2 __attribute__((ext_vector_type(2)));

__device__ __forceinline__ f2 pkfma(f2 a, f2 b, f2 c) {
#if __has_builtin(__builtin_elementwise_fma)
    return __builtin_elementwise_fma(a, b, c);
#else
    f2 r; r.x = fmaf(a.x, b.x, c.x); r.y = fmaf(a.y, b.y, c.y); return r;
#endif
}

__device__ __forceinline__ float frcp(float x) {
    return __builtin_amdgcn_rcpf(x);
}

__device__ __forceinline__ float fsig(float x) {
    float e = __builtin_amdgcn_exp2f(x * -1.4426950408889634f);
    return frcp(1.0f + e);
}

// ---------------------------------------------------------------------------
// Packed-FP32 + bank-swizzled LDS (R6 math, bit-identical) + two-tile
// software pipeline for LEVEL 0 ONLY.
// R5: pkfma halved VALU issue; f2 LDS layout -> 20M conflicts, net 0.
// R6: float4-column {mu1,mu2,xx,xy} + XOR swizzle -> conflicts 0, L0 181 µs,
//     total 414.5 (best).
// R7: LDS-staged loads REGRESSED: strided loads are L2-absorbed.
// R8: pinned weight VGPRs: no codegen change — remat theory falsified.
// R9: PIPE2 @ launch_bounds(256,4) SPILLED (VGPR stuck 64, WRITE_SIZE
//     68->160 MB = scratch traffic) — pipeline win eaten by spills; L1
//     (5 quantities) spilled worst. Total 444.
// R10: PIPE2 only for L0 (SKIPYY, 4 quantities) with launch_bounds(256,3):
//     VGPR budget ~170 fits both tile arrays (~146 needed). Measured
//     occupancy at the 4-block cap was only ~2.8 blocks anyway, so the
//     3-block cap sacrifices little wave supply for real latency overlap.
//     L1 reverts to the proven non-piped R6 path at (256,4).
// LDS: planes 8192 f + yy 2048 f = 40960 B.
// History: R1 keep-alive-on-loads -5 µs; R2 grid.sync raced; R4 tail
// serialization +35 µs. Structure = proven 5 launches + finalize.
// ---------------------------------------------------------------------------
template <int N, int M, bool SIG, bool POOL, bool SKIPYY, bool NARROW, bool PIPE2>
__global__ __launch_bounds__(256, PIPE2 ? 3 : 4)
void ssim_kernel(const float* __restrict__ X, const float* __restrict__ Y,
                 float* __restrict__ accSsim, float* __restrict__ accCs,
                 float* __restrict__ poolX, float* __restrict__ poolY) {
    __shared__ float smem[10240];              // 40960 B
    const int tid = threadIdx.x;
    const int img = blockIdx.z;
    const int ox0 = NARROW ? 0 : blockIdx.x * TW;
    const int c  = tid & 127;      // tile-local column 0..127
    const int s  = tid >> 7;       // strip 0/1 (rows 8s .. 8s+7)
    const int ci = ox0 + c;        // global column
    constexpr int half = N >> 1;
    const int powned = NARROW ? N : min(TW, N - ox0);  // pool column ownership
    const long base = (long)img * N * N;
    const float* __restrict__ Xb = X + base;
    const float* __restrict__ Yb = Y + base;

    f2 WP[11];
#pragma unroll
    for (int t = 0; t < 11; t++) WP[t] = (f2){W[t], W[t]};

    // ---- phase 1 load: 18 rows/thread into registers -----------------------
    auto load_tile = [&](int oy0, f2* xy) {
        const bool interior = (oy0 + 25 < N) && (ox0 + 127 < N);
        if (interior) {
            const float* __restrict__ xp = Xb + (long)(oy0 + 8 * s) * N + ci;
            const float* __restrict__ yp = Yb + (long)(oy0 + 8 * s) * N + ci;
#pragma unroll
            for (int i = 0; i < 18; i++) {
                xy[i].x = xp[(long)i * N];
                xy[i].y = yp[(long)i * N];
            }
        } else {
            const int cic = min(ci, N - 1);
#pragma unroll
            for (int i = 0; i < 18; i++) {
                int rc = min(oy0 + 8 * s + i, N - 1);
                xy[i].x = Xb[(long)rc * N + cic];
                xy[i].y = Yb[(long)rc * N + cic];
            }
        }
        __builtin_amdgcn_sched_barrier(0);   // pin issue point (pipeline fence)
    };

    // ---- phase 1b/1c: sigmoid, vertical filter, pool, LDS store ------------
    auto vert_store = [&](int oy0, f2* xy) {
        if constexpr (SIG) {
#pragma unroll
            for (int i = 0; i < 18; i++) xy[i].x = fsig(xy[i].x);
        }
        f2 a01[8], a23[8];
        float ayy[SKIPYY ? 1 : 8];
#pragma unroll
        for (int o = 0; o < 8; o++) {
            a01[o] = (f2){0.f, 0.f};
            a23[o] = (f2){0.f, 0.f};
            if constexpr (!SKIPYY) ayy[o] = 0.f;
        }
#pragma unroll
        for (int i = 0; i < 18; i++) {
            f2 v01 = xy[i];
            f2 xb = (f2){v01.x, v01.x};
            f2 v23 = xb * v01;                       // {x*x, x*y} packed mul
            float yy;
            if constexpr (!SKIPYY) yy = v01.y * v01.y;
#pragma unroll
            for (int o = 0; o < 8; o++) {
                int t = i - o;
                if (t >= 0 && t < 11) {              // folds statically
                    a01[o] = pkfma(WP[t], v01, a01[o]);
                    a23[o] = pkfma(WP[t], v23, a23[o]);
                    if constexpr (!SKIPYY) ayy[o] = fmaf(W[t], yy, ayy[o]);
                }
            }
        }
        if constexpr (POOL) {
            float cx[4], cy[4];
#pragma unroll
            for (int p = 0; p < 4; p++) {
                cx[p] = xy[2 * p].x + xy[2 * p + 1].x;
                cy[p] = xy[2 * p].y + xy[2 * p + 1].y;
            }
#pragma unroll
            for (int p = 0; p < 4; p++) {
                float rx = __shfl_down(cx[p], 1, 64);   // column c+1 (same wave)
                float ry = __shfl_down(cy[p], 1, 64);
                if (!(c & 1) && c < powned) {
                    int orow = (oy0 + 8 * s + 2 * p) >> 1;
                    int ocol = ci >> 1;
                    long pb = (long)img * half * half + (long)orow * half + ocol;
                    poolX[pb] = 0.25f * (cx[p] + rx);
                    poolY[pb] = 0.25f * (cy[p] + ry);
                }
            }
        }
        // LDS write: float4 column {mu1,mu2,xx,xy} at XOR-swizzled position
        // main plane floats [0,8192); yy scalar plane [8192,10240)
#pragma unroll
        for (int o = 0; o < 8; o++) {
            int rr = 8 * s + o;
            int phys = c ^ (((c >> 3) + rr) & 7);       // bijective per row
            float4 v;
            v.x = a01[o].x; v.y = a01[o].y; v.z = a23[o].x; v.w = a23[o].y;
            *(float4*)&smem[rr * 512 + phys * 4] = v;
            if constexpr (!SKIPYY) {
                int ch = c >> 2;
                int pc = ch ^ (((ch >> 3) + rr) & 7);   // f4-chunk swizzle
                smem[8192 + rr * 128 + pc * 4 + (c & 3)] = ayy[o];
            }
        }
    };

    // ---- phase 2: horizontal filter + SSIM map -----------------------------
    const float C1 = 1e-4f, C2 = 9e-4f;
    auto phase2 = [&](int oy0, float& scs, float& sss) {
        const int r = tid >> 4;    // output row within tile
        const int k = tid & 15;    // 8-px column segment
        if (k < 15) {              // segment base 8k must be < 118
            f2 a01h[8], a23h[8];
#pragma unroll
            for (int j = 0; j < 8; j++) {
                a01h[j] = (f2){0.f, 0.f};
                a23h[j] = (f2){0.f, 0.f};
            }
#pragma unroll
            for (int m = 0; m < 18; m++) {
                int col = 8 * k + m;                    // may be 128/129 @k=14
                int g = (k + (m >> 3) + r) & 7;         // == ((col>>3)+r)&7
                int phys = (col ^ g) & 127;             // wrap: garbage masked
                const float4 v4 = *(const float4*)&smem[r * 512 + phys * 4];
                f2 v01 = (f2){v4.x, v4.y};
                f2 v23 = (f2){v4.z, v4.w};
#pragma unroll
                for (int j = 0; j < 8; j++) {
                    int t = m - j;
                    if (t >= 0 && t < 11) {             // folds statically
                        a01h[j] = pkfma(WP[t], v01, a01h[j]);
                        a23h[j] = pkfma(WP[t], v23, a23h[j]);
                    }
                }
            }
            float oyy[8];
            if constexpr (!SKIPYY) {
                float rgs[20];
#pragma unroll
                for (int j5 = 0; j5 < 5; j5++) {
                    int ch = 2 * k + j5;                // may be 32 @k=14
                    int pc = (ch ^ (((ch >> 3) + r) & 7)) & 31;
                    const float4 v4 = *(const float4*)&smem[8192 + r * 128 + pc * 4];
                    rgs[4 * j5 + 0] = v4.x; rgs[4 * j5 + 1] = v4.y;
                    rgs[4 * j5 + 2] = v4.z; rgs[4 * j5 + 3] = v4.w;
                }
#pragma unroll
                for (int j = 0; j < 8; j++) {
                    float a = 0.f;
#pragma unroll
                    for (int t = 0; t < 11; t++) a = fmaf(W[t], rgs[j + t], a);
                    oyy[j] = a;
                }
            }
            const int gy = oy0 + r;
            const bool rowok = gy < M;          // uniform per thread, hoisted
#pragma unroll
            for (int j = 0; j < 8; j++) {
                int lc = 8 * k + j;
                int gx = ox0 + lc;
                if (lc < TW && gx < M && rowok) {
                    float mu1 = a01h[j].x, mu2 = a01h[j].y;
                    float exx = a23h[j].x, exy = a23h[j].y;
                    float m11 = mu1 * mu1, m22 = mu2 * mu2, m12 = mu1 * mu2;
                    float s1 = exx - m11;
                    float s2 = SKIPYY ? (mu2 - m22) : (oyy[j] - m22);
                    float s12 = exy - m12;
                    float cs = (2.f * s12 + C2) * frcp(s1 + s2 + C2);
                    float ssim = (2.f * m12 + C1) * frcp(m11 + m22 + C1) * cs;
                    scs += cs; sss += ssim;
                }
            }
        }
    };

    float scs = 0.f, sss = 0.f;
    if constexpr (PIPE2) {
        const int oyA = (int)(blockIdx.y * 2) * TH;
        const int oyB = oyA + TH;
        f2 xyA[18], xyB[18];
        load_tile(oyA, xyA);
        vert_store(oyA, xyA);
        __syncthreads();
        load_tile(oyB, xyB);       // B loads fly during phase2(A)
        phase2(oyA, scs, sss);
        __syncthreads();           // A's LDS reads done -> B may overwrite
        vert_store(oyB, xyB);      // vmcnt wait lands here (latency hidden)
        __syncthreads();
        phase2(oyB, scs, sss);
    } else {
        const int oy0 = blockIdx.y * TH;
        f2 xy[18];
        load_tile(oy0, xy);
        vert_store(oy0, xy);
        __syncthreads();
        phase2(oy0, scs, sss);
    }

    // block reduction (reuse smem after barrier); one atomic per block
    for (int off = 32; off > 0; off >>= 1) {
        scs += __shfl_down(scs, off, 64);
        sss += __shfl_down(sss, off, 64);
    }
    __syncthreads();
    int lane = tid & 63, wv = tid >> 6;
    if (lane == 0) { smem[wv] = scs; smem[4 + wv] = sss; }
    __syncthreads();
    if (tid == 0) {
        atomicAdd(&accCs[img],   smem[0] + smem[1] + smem[2] + smem[3]);
        atomicAdd(&accSsim[img], smem[4] + smem[5] + smem[6] + smem[7]);
    }
}

// acc layout: level l -> [l*2*NIMG .. +NIMG) ssim sums, [+NIMG .. +2*NIMG) cs sums
__global__ __launch_bounds__(128)
void finalize_kernel(const float* __restrict__ acc, float* __restrict__ out) {
    const float wts[5] = {0.0448f, 0.2856f, 0.3001f, 0.2363f, 0.1333f};
    const int Ms[5] = {502, 246, 118, 54, 22};
    int t = threadIdx.x;
    float v = 0.f;
    if (t < NIMG) {
        float prod = 1.f;
#pragma unroll
        for (int l = 0; l < 5; l++) {
            float inv = 1.0f / ((float)Ms[l] * (float)Ms[l]);
            float m = (l < 4) ? acc[l * 2 * NIMG + NIMG + t] * inv   // cs mean
                              : acc[l * 2 * NIMG + t] * inv;          // ssim mean
            m = fmaxf(m, 0.f);                                        // relu
            prod *= powf(m, wts[l]);
        }
        v = prod;
    }
    for (int off = 32; off > 0; off >>= 1) v += __shfl_down(v, off, 64);
    __shared__ float red[2];
    if ((t & 63) == 0) red[t >> 6] = v;
    __syncthreads();
    if (t == 0) out[0] = 1.0f - (red[0] + red[1]) / (float)NIMG;
}

extern "C" void kernel_launch(void* const* d_in, const int* in_sizes, int n_in,
                              void* d_out, int out_size, void* d_ws, size_t ws_size,
                              hipStream_t stream) {
    const float* logits = (const float*)d_in[0];
    const float* targets = (const float*)d_in[1];
    float* out = (float*)d_out;
    float* ws = (float*)d_ws;

    // workspace layout (floats)
    float* acc = ws;                               // 5*2*116 = 1160 floats
    size_t off = 1280;
    float* X1 = ws + off; off += (size_t)NIMG * 256 * 256;
    float* Y1 = ws + off; off += (size_t)NIMG * 256 * 256;
    float* X2 = ws + off; off += (size_t)NIMG * 128 * 128;
    float* Y2 = ws + off; off += (size_t)NIMG * 128 * 128;
    float* X3 = ws + off; off += (size_t)NIMG * 64 * 64;
    float* Y3 = ws + off; off += (size_t)NIMG * 64 * 64;
    float* X4 = ws + off; off += (size_t)NIMG * 32 * 32;
    float* Y4 = ws + off; off += (size_t)NIMG * 32 * 32;

    hipMemsetAsync(acc, 0, 1160 * sizeof(float), stream);

    // level 0: sigmoid + pool fused, binary targets -> SKIPYY, PIPE2 (16 pairs)
    {
        dim3 grid((512 + TW - 1) / TW, 512 / TH / 2, NIMG);
        ssim_kernel<512, 502, true, true, true, false, true><<<grid, 256, 0, stream>>>(
            logits, targets, acc, acc + NIMG, X1, Y1);
    }
    // level 1: N=256, wide tiles (non-piped R6 path — 5 quantities spill)
    {
        dim3 grid((256 + TW - 1) / TW, 256 / TH, NIMG);
        ssim_kernel<256, 246, false, true, false, false, false><<<grid, 256, 0, stream>>>(
            X1, Y1, acc + 2 * NIMG, acc + 3 * NIMG, X2, Y2);
    }
    // level 2: N=128, single x-tile
    {
        dim3 grid(1, 128 / TH, NIMG);
        ssim_kernel<128, 118, false, true, false, true, false><<<grid, 256, 0, stream>>>(
            X2, Y2, acc + 4 * NIMG, acc + 5 * NIMG, X3, Y3);
    }
    // level 3: N=64, single x-tile
    {
        dim3 grid(1, 64 / TH, NIMG);
        ssim_kernel<64, 54, false, true, false, true, false><<<grid, 256, 0, stream>>>(
            X3, Y3, acc + 6 * NIMG, acc + 7 * NIMG, X4, Y4);
    }
    // level 4: N=32, single x-tile, no pool
    {
        dim3 grid(1, 32 / TH, NIMG);
        ssim_kernel<32, 22, false, false, false, true, false><<<grid, 256, 0, stream>>>(
            X4, Y4, acc + 8 * NIMG, acc + 9 * NIMG, nullptr, nullptr);
    }

    finalize_kernel<<<1, 128, 0, stream>>>(acc, out);
}